// Round 4
// baseline (548.401 us; speedup 1.0000x reference)
//
#include <hip/hip_runtime.h>

typedef unsigned short u16;
typedef unsigned int u32;
typedef __attribute__((ext_vector_type(8))) short bfrag;   // 8 x bf16 (4 VGPRs)
typedef __attribute__((ext_vector_type(4))) float ffrag;   // 4 x f32

constexpr int B_ = 16, CIN = 64, COUT = 64, G = 8, CPG = 8;
constexpr int H = 130, W = 130, HO = 128, WO = 128;
constexpr int OFFC = 144;               // G*2*3*3
constexpr int PLANE_IN = H * W;         // 16900
constexpr int PLANE_OUT = HO * WO;      // 16384

// ws layout:
//   u16   wdB[64*576] @0       : wdB[co*576 + t*64 + ci] = bf16(wd[co][ci][t])
//   u16   wB1[64*576] @147456B : wB1[co*576 + t*64 + ci] = bf16(w1[co][ci][t])
//   u16   wB2[144*64] @221184B : wB2[oc*64 + ci]         = bf16(w2[oc][ci])
//   u16   xt[16*16900*64] @262144B : NHWC bf16 x (if ws_size permits)
constexpr size_t WB1_BYTE = 36864 * 4;
constexpr size_t WB2_BYTE = WB1_BYTE + 36864 * 2;
constexpr size_t XT_BYTE  = 262144;
constexpr size_t XT_SIZE  = (size_t)B_ * PLANE_IN * 64 * 2;   // 34.6 MB

__device__ __forceinline__ u16 f2bf(float f) {
    union { u32 u; float f; } t; t.f = f;
    return (u16)((t.u + 0x7FFFu + ((t.u >> 16) & 1u)) >> 16);  // RNE
}
__device__ __forceinline__ float bf2f(short h) {
    union { u32 u; float f; } t; t.u = ((u32)(u16)h) << 16;
    return t.f;
}

// K0: weight prep (transpose + bf16 conversion).
__global__ void prep_weights(const float* __restrict__ w1,
                             const float* __restrict__ wd,
                             const float* __restrict__ w2,
                             float* __restrict__ wsf) {
    u16* wdB = (u16*)wsf;
    u16* wB1 = (u16*)((char*)wsf + WB1_BYTE);
    u16* wB2 = (u16*)((char*)wsf + WB2_BYTE);
    int idx = blockIdx.x * 256 + threadIdx.x;
    if (idx < 36864) {                        // wdB[co*576 + t*64 + ci]
        int co = idx / 576, r = idx % 576;
        int t = r >> 6, ci = r & 63;
        wdB[idx] = f2bf(wd[(co * 64 + ci) * 9 + t]);
    } else if (idx < 73728) {                 // wB1[co*576 + t*64 + ci]
        int j = idx - 36864;
        int co = j / 576, r = j % 576;
        int t = r >> 6, ci = r & 63;
        wB1[j] = f2bf(w1[(co * 64 + ci) * 9 + t]);
    } else if (idx < 82944) {                 // wB2[oc*64+ci]
        int j = idx - 73728;
        wB2[j] = f2bf(w2[j]);
    }
}

// K0b: x NCHW f32 -> NHWC bf16.
__global__ __launch_bounds__(256) void x_to_nhwc(const float* __restrict__ x,
                                                 u16* __restrict__ xt) {
    int p = blockIdx.x * 256 + threadIdx.x;          // global pixel
    if (p >= B_ * PLANE_IN) return;
    int b = p / PLANE_IN, pp = p % PLANE_IN;
    const float* xb = x + (size_t)b * CIN * PLANE_IN + pp;
    u16* dst = xt + (size_t)p * 64;
    #pragma unroll
    for (int oct = 0; oct < 8; ++oct) {
        union { u16 h[8]; uint4 q; } pk;
        #pragma unroll
        for (int j = 0; j < 8; ++j)
            pk.h[j] = f2bf(xb[(size_t)(oct * 8 + j) * PLANE_IN]);
        *(uint4*)(dst + oct * 8) = pk.q;
    }
}

// LDS for conv12: linear 128B rows + XOR swizzle byte ^= (p&7)<<4 (T2).
union ConvSmem {
    char xsb[324 * 128];       // 41472 B : halo tile [p][ci] swizzled
    char hsb[4][64 * 128];     // 32768 B : per-wave h buffer [pix][ci] swizzled
};
__device__ __forceinline__ int swz128(int row, int bytecol) {
    return row * 128 + (bytecol ^ ((row & 7) << 4));
}

// K1: fused conv1 (3x3 VALID, 64->64) + conv2 (1x1, 64->144) via bf16 MFMA.
template<bool XT>
__global__ __launch_bounds__(256) void conv12(const float* __restrict__ x,
                                              const u16* __restrict__ xt,
                                              const float* __restrict__ b1,
                                              const float* __restrict__ b2,
                                              const float* __restrict__ wsf,
                                              float* __restrict__ off_out) {
    __shared__ ConvSmem sm;
    const u16* wB1 = (const u16*)((const char*)wsf + WB1_BYTE);
    const u16* wB2 = (const u16*)((const char*)wsf + WB2_BYTE);
    const int b = blockIdx.z;
    const int y0 = blockIdx.y * 16, x0 = blockIdx.x * 16;
    const int tid = threadIdx.x;
    const int wave = tid >> 6, lane = tid & 63;
    const int n16 = lane & 15, quad = lane >> 4;

    if constexpr (XT) {
        const u16* xtb = xt + (size_t)b * PLANE_IN * 64;
        for (int idx = tid; idx < 324 * 8; idx += 256) {
            int p = idx >> 3, oct = idx & 7;
            *(bfrag*)(sm.xsb + swz128(p, oct * 16)) =
                *(const bfrag*)&xtb[((size_t)(y0 + p / 18) * W + x0 + p % 18) * 64 + oct * 8];
        }
    } else {
        const float* xb = x + (size_t)b * CIN * PLANE_IN;
        for (int idx = tid; idx < 324 * 64; idx += 256) {
            int ci = idx / 324, p = idx % 324;
            float v = xb[(size_t)ci * PLANE_IN + (y0 + p / 18) * W + (x0 + p % 18)];
            *(u16*)(sm.xsb + swz128(p, ci * 2)) = f2bf(v);
        }
    }
    __syncthreads();

    ffrag acc[4][4];
    #pragma unroll
    for (int nt = 0; nt < 4; ++nt) {
        float bv = b1[nt * 16 + n16];
        #pragma unroll
        for (int mt = 0; mt < 4; ++mt) acc[mt][nt] = ffrag{bv, bv, bv, bv};
    }

    #pragma unroll
    for (int s = 0; s < 18; ++s) {                    // K=576 in 18 slices of 32
        const int tap = s >> 1, cib = (s & 1) * 32;
        const int ti = tap / 3, tj = tap % 3;
        bfrag a[4], bb[4];
        #pragma unroll
        for (int mt = 0; mt < 4; ++mt) {              // A[m=lane&15][k=quad*8+j]
            int p = (wave * 4 + mt + ti) * 18 + n16 + tj;
            a[mt] = *(const bfrag*)(sm.xsb + swz128(p, cib * 2 + quad * 16));
        }
        #pragma unroll
        for (int nt = 0; nt < 4; ++nt)                // B[n=lane&15][k=quad*8+j]
            bb[nt] = *(const bfrag*)&wB1[(nt * 16 + n16) * 576 + tap * 64 + cib + quad * 8];
        #pragma unroll
        for (int mt = 0; mt < 4; ++mt)
            #pragma unroll
            for (int nt = 0; nt < 4; ++nt)
                acc[mt][nt] = __builtin_amdgcn_mfma_f32_16x16x32_bf16(
                    a[mt], bb[nt], acc[mt][nt], 0, 0, 0);
    }

    __syncthreads();

    #pragma unroll
    for (int mt = 0; mt < 4; ++mt)
        #pragma unroll
        for (int nt = 0; nt < 4; ++nt)
            #pragma unroll
            for (int r = 0; r < 4; ++r)
                *(u16*)(sm.hsb[wave] + swz128(mt * 16 + quad * 4 + r, (nt * 16 + n16) * 2))
                    = f2bf(acc[mt][nt][r]);
    __syncthreads();

    bfrag a2[4][2];
    #pragma unroll
    for (int mt = 0; mt < 4; ++mt)
        #pragma unroll
        for (int s2 = 0; s2 < 2; ++s2)
            a2[mt][s2] = *(const bfrag*)(sm.hsb[wave]
                        + swz128(mt * 16 + n16, s2 * 64 + quad * 16));

    float* offb = off_out + (size_t)b * OFFC * PLANE_OUT;
    #pragma unroll 1
    for (int nt2 = 0; nt2 < 9; ++nt2) {               // N2=144 in 9 n-tiles
        bfrag b2f[2];
        #pragma unroll
        for (int s2 = 0; s2 < 2; ++s2)
            b2f[s2] = *(const bfrag*)&wB2[(nt2 * 16 + n16) * 64 + s2 * 32 + quad * 8];
        float bv = b2[nt2 * 16 + n16];
        #pragma unroll
        for (int mt = 0; mt < 4; ++mt) {
            ffrag acc2 = ffrag{bv, bv, bv, bv};
            acc2 = __builtin_amdgcn_mfma_f32_16x16x32_bf16(a2[mt][0], b2f[0], acc2, 0, 0, 0);
            acc2 = __builtin_amdgcn_mfma_f32_16x16x32_bf16(a2[mt][1], b2f[1], acc2, 0, 0, 0);
            float* dst = offb + (size_t)(nt2 * 16 + n16) * PLANE_OUT
                       + (y0 + wave * 4 + mt) * WO + x0 + quad * 4;
            *(ffrag*)dst = acc2;
        }
    }
}

__device__ __forceinline__ bfrag interp4(const bfrag* q, const float* w) {
    union { u16 h[8]; bfrag f; } pk;
    #pragma unroll
    for (int j = 0; j < 8; ++j) {
        float v = w[0] * bf2f(q[0][j]) + w[1] * bf2f(q[1][j])
                + w[2] * bf2f(q[2][j]) + w[3] * bf2f(q[3][j]);
        pk.h[j] = f2bf(v);
    }
    return pk.f;
}

// K2: deformable conv via bf16 MFMA with LDS-staged bilinear gathers.
// Block = 256 thr (4 waves), tile 8 rows x 16 cols; wave owns rows wave*2,+1.
// Stage once per block: x halo tile rows [y0-2, y0+11], cols [x0-2, x0+19]
// (14x22 px x 64ch bf16 = 39.4 KB LDS; covers taps 0..2 + offsets within +-2px,
// which is ~all of them since off ~ N(0, 0.1px)). Gathers then hit LDS
// (ds_read_b128, XOR-swizzled -> 16B/lane floor) instead of 64-line L1 storms.
// Rare out-of-tile samples (arbitrary offsets) take an execz-skipped global
// fallback with identical clip/mask semantics.
constexpr int TR = 14, TC = 22, TILE_PX = TR * TC;    // 308 px

__device__ __forceinline__ bfrag lds_px(const char* xls, int p, int g) {
    return *(const bfrag*)(xls + p * 128 + ((g * 16) ^ ((p & 7) << 4)));
}

template<bool XT>
__global__ __launch_bounds__(256, 4) void deform_k(const float* __restrict__ x,
                                                   const u16* __restrict__ xt,
                                                   const float* __restrict__ wsf,
                                                   const float* __restrict__ off_in,
                                                   float* __restrict__ y_out) {
    __shared__ char xls[TILE_PX * 128];               // 39424 B
    const u16* wdB = (const u16*)wsf;

    const int wg = blockIdx.x;
    const int swz = (wg & 7) * 256 + (wg >> 3);       // XCD-contiguous, bijective (2048%8==0)
    const int b = swz >> 7, sp = swz & 127;
    const int y0 = (sp >> 3) * 8, x0 = (sp & 7) * 16;
    const int ylo = y0 - 2, xlo = x0 - 2;

    const int tid = threadIdx.x;
    const int wave = tid >> 6, lane = tid & 63;
    const int n16 = lane & 15, quad = lane >> 4;
    const int wo = x0 + n16;

    const float* offbase = off_in + (size_t)b * OFFC * PLANE_OUT + x0 + n16;
    const u16* xtb = xt + (size_t)b * PLANE_IN * 64;
    const float* xb = x + (size_t)b * CIN * PLANE_IN;

    if constexpr (XT) {
        // stage halo tile; clamped coords for never-read OOB rows/cols
        for (int idx = tid; idx < TILE_PX * 8; idx += 256) {
            int oct = idx & 7, pix = idx >> 3;
            int ty = pix / TC, tx = pix % TC;
            int iy = min(max(ylo + ty, 0), H - 1);
            int ix = min(max(xlo + tx, 0), W - 1);
            *(bfrag*)(xls + pix * 128 + ((oct * 16) ^ ((pix & 7) << 4)))
                = *(const bfrag*)&xtb[((size_t)(iy * W + ix)) * 64 + oct * 8];
        }
        __syncthreads();
    }

    ffrag acc[2][4];
    #pragma unroll
    for (int mt = 0; mt < 2; ++mt)
        #pragma unroll
        for (int nt = 0; nt < 4; ++nt) acc[mt][nt] = ffrag{0.f, 0.f, 0.f, 0.f};

    // prefetched offsets for the upcoming tap; tk = mt*2 + half
    float pdy[4], pdx[4];
    #pragma unroll
    for (int tk = 0; tk < 4; ++tk) {
        const int mt = tk >> 1, g = quad + (tk & 1) * 4;
        const float* ob = offbase + (y0 + wave * 2 + mt) * WO
                        + (size_t)(g * 9 * 2) * PLANE_OUT;      // t = 0
        pdy[tk] = ob[0];
        pdx[tk] = ob[PLANE_OUT];
    }

    #pragma unroll 1
    for (int t = 0; t < 9; ++t) {
        const int ki = t / 3, kj = t % 3;

        float dyv[4], dxv[4];
        #pragma unroll
        for (int tk = 0; tk < 4; ++tk) { dyv[tk] = pdy[tk]; dxv[tk] = pdx[tk]; }

        if (t < 8) {                                  // prefetch next tap's offsets
            #pragma unroll
            for (int tk = 0; tk < 4; ++tk) {
                const int mt = tk >> 1, g = quad + (tk & 1) * 4;
                const float* ob = offbase + (y0 + wave * 2 + mt) * WO
                                + (size_t)((g * 9 + t + 1) * 2) * PLANE_OUT;
                pdy[tk] = ob[0];
                pdx[tk] = ob[PLANE_OUT];
            }
        }

        bfrag bw0[4], bw1[4];                         // B-operands early (L2-hot)
        #pragma unroll
        for (int nt = 0; nt < 4; ++nt) {
            const u16* wp = &wdB[(size_t)(nt * 16 + n16) * 576 + t * 64 + quad * 8];
            bw0[nt] = *(const bfrag*)wp;
            bw1[nt] = *(const bfrag*)(wp + 32);
        }

        bfrag frag[4];
        #pragma unroll
        for (int tk = 0; tk < 4; ++tk) {
            const int mt = tk >> 1, g = quad + (tk & 1) * 4;
            const int ho = y0 + wave * 2 + mt;
            float py = dyv[tk] + (float)(ho + ki);
            float px = dxv[tk] + (float)(wo + kj);
            float y0f = floorf(py), x0f = floorf(px);
            float ly = py - y0f, lx = px - x0f;
            int yi0 = (int)y0f, xi0 = (int)x0f;
            int yi1 = yi0 + 1, xi1 = xi0 + 1;
            float vy0 = (yi0 >= 0 && yi0 < H) ? 1.f : 0.f;
            float vy1 = (yi1 >= 0 && yi1 < H) ? 1.f : 0.f;
            float vx0 = (xi0 >= 0 && xi0 < W) ? 1.f : 0.f;
            float vx1 = (xi1 >= 0 && xi1 < W) ? 1.f : 0.f;
            float wq[4];
            wq[0] = (1.f - ly) * (1.f - lx) * vy0 * vx0;
            wq[1] = (1.f - ly) * lx         * vy0 * vx1;
            wq[2] = ly * (1.f - lx)         * vy1 * vx0;
            wq[3] = ly * lx                 * vy1 * vx1;
            int yc0 = min(max(yi0, 0), H - 1), yc1 = min(max(yi1, 0), H - 1);
            int xc0 = min(max(xi0, 0), W - 1), xc1 = min(max(xi1, 0), W - 1);

            if constexpr (XT) {
                int ry0 = yc0 - ylo, ry1 = yc1 - ylo;
                int rx0 = xc0 - xlo, rx1 = xc1 - xlo;
                bool intile = ((u32)ry0 < TR) & ((u32)ry1 < TR)
                            & ((u32)rx0 < TC) & ((u32)rx1 < TC);
                int p00 = ry0 * TC + rx0, p01 = ry0 * TC + rx1;
                int p10 = ry1 * TC + rx0, p11 = ry1 * TC + rx1;
                p00 = min(max(p00, 0), TILE_PX - 1);
                p01 = min(max(p01, 0), TILE_PX - 1);
                p10 = min(max(p10, 0), TILE_PX - 1);
                p11 = min(max(p11, 0), TILE_PX - 1);
                bfrag q[4];
                q[0] = lds_px(xls, p00, g);
                q[1] = lds_px(xls, p01, g);
                q[2] = lds_px(xls, p10, g);
                q[3] = lds_px(xls, p11, g);
                frag[tk] = interp4(q, wq);
                if (!intile) {                        // execz-skipped in practice
                    bfrag qg[4];
                    qg[0] = *(const bfrag*)&xtb[(size_t)(yc0 * W + xc0) * 64 + g * 8];
                    qg[1] = *(const bfrag*)&xtb[(size_t)(yc0 * W + xc1) * 64 + g * 8];
                    qg[2] = *(const bfrag*)&xtb[(size_t)(yc1 * W + xc0) * 64 + g * 8];
                    qg[3] = *(const bfrag*)&xtb[(size_t)(yc1 * W + xc1) * 64 + g * 8];
                    frag[tk] = interp4(qg, wq);
                }
            } else {
                int i00 = yc0 * W + xc0, i01 = yc0 * W + xc1;
                int i10 = yc1 * W + xc0, i11 = yc1 * W + xc1;
                const float* xg = xb + (size_t)g * CPG * PLANE_IN;
                union { u16 h[8]; bfrag f; } pk;
                #pragma unroll
                for (int cc = 0; cc < 8; ++cc) {
                    const float* xp = xg + cc * PLANE_IN;
                    float v = wq[0] * xp[i00] + wq[1] * xp[i01]
                            + wq[2] * xp[i10] + wq[3] * xp[i11];
                    pk.h[cc] = f2bf(v);
                }
                frag[tk] = pk.f;
            }
        }

        #pragma unroll
        for (int nt = 0; nt < 4; ++nt)
            #pragma unroll
            for (int mt = 0; mt < 2; ++mt) {
                acc[mt][nt] = __builtin_amdgcn_mfma_f32_16x16x32_bf16(
                    frag[mt * 2 + 0], bw0[nt], acc[mt][nt], 0, 0, 0);
                acc[mt][nt] = __builtin_amdgcn_mfma_f32_16x16x32_bf16(
                    frag[mt * 2 + 1], bw1[nt], acc[mt][nt], 0, 0, 0);
            }
    }

    // epilogue: lane holds D[m=quad*4+r][n=n16]; m = pixel col, n = co-in-tile
    float* yb = y_out + (size_t)b * COUT * PLANE_OUT;
    #pragma unroll
    for (int nt = 0; nt < 4; ++nt)
        #pragma unroll
        for (int mt = 0; mt < 2; ++mt) {
            float* dst = yb + (size_t)(nt * 16 + n16) * PLANE_OUT
                       + (y0 + wave * 2 + mt) * WO + x0 + quad * 4;
            *(ffrag*)dst = acc[mt][nt];
        }
}

extern "C" void kernel_launch(void* const* d_in, const int* in_sizes, int n_in,
                              void* d_out, int out_size, void* d_ws, size_t ws_size,
                              hipStream_t stream) {
    const float* x  = (const float*)d_in[0];
    const float* w1 = (const float*)d_in[1];
    const float* b1 = (const float*)d_in[2];
    const float* w2 = (const float*)d_in[3];
    const float* b2 = (const float*)d_in[4];
    const float* wd = (const float*)d_in[5];
    float* y_out = (float*)d_out;
    float* off_out = y_out + (size_t)B_ * COUT * PLANE_OUT;   // (y, off) concat
    float* wsf = (float*)d_ws;
    u16* xt = (u16*)((char*)d_ws + XT_BYTE);
    const bool use_xt = ws_size >= XT_BYTE + XT_SIZE;

    prep_weights<<<324, 256, 0, stream>>>(w1, wd, w2, wsf);
    if (use_xt) {
        x_to_nhwc<<<(B_ * PLANE_IN + 255) / 256, 256, 0, stream>>>(x, xt);
        conv12<true><<<dim3(8, 8, B_), 256, 0, stream>>>(x, xt, b1, b2, wsf, off_out);
        deform_k<true><<<2048, 256, 0, stream>>>(x, xt, wsf, off_out, y_out);
    } else {
        conv12<false><<<dim3(8, 8, B_), 256, 0, stream>>>(x, xt, b1, b2, wsf, off_out);
        deform_k<false><<<2048, 256, 0, stream>>>(x, xt, wsf, off_out, y_out);
    }
}

// Round 5
// 431.424 us; speedup vs baseline: 1.2711x; 1.2711x over previous
//
#include <hip/hip_runtime.h>

typedef unsigned short u16;
typedef unsigned int u32;
typedef __attribute__((ext_vector_type(8))) short bfrag;   // 8 x bf16 (4 VGPRs)
typedef __attribute__((ext_vector_type(4))) float ffrag;   // 4 x f32

constexpr int B_ = 16, CIN = 64, COUT = 64, G = 8, CPG = 8;
constexpr int H = 130, W = 130, HO = 128, WO = 128;
constexpr int OFFC = 144;               // G*2*3*3
constexpr int PLANE_IN = H * W;         // 16900
constexpr int PLANE_OUT = HO * WO;      // 16384

// ws layout:
//   u16   wdB[64*576] @0       : wdB[co*576 + t*64 + ci] = bf16(wd[co][ci][t])
//   u16   wB1[64*576] @147456B : wB1[co*576 + t*64 + ci] = bf16(w1[co][ci][t])
//   u16   wB2[144*64] @221184B : wB2[oc*64 + ci]         = bf16(w2[oc][ci])
//   u16   xt[16*16900*64] @262144B : NHWC bf16 x (if ws_size permits)
constexpr size_t WB1_BYTE = 36864 * 4;
constexpr size_t WB2_BYTE = WB1_BYTE + 36864 * 2;
constexpr size_t XT_BYTE  = 262144;
constexpr size_t XT_SIZE  = (size_t)B_ * PLANE_IN * 64 * 2;   // 34.6 MB

__device__ __forceinline__ u16 f2bf(float f) {
    union { u32 u; float f; } t; t.f = f;
    return (u16)((t.u + 0x7FFFu + ((t.u >> 16) & 1u)) >> 16);  // RNE
}
__device__ __forceinline__ float bf2f(short h) {
    union { u32 u; float f; } t; t.u = ((u32)(u16)h) << 16;
    return t.f;
}

// K0: weight prep (transpose + bf16 conversion).
__global__ void prep_weights(const float* __restrict__ w1,
                             const float* __restrict__ wd,
                             const float* __restrict__ w2,
                             float* __restrict__ wsf) {
    u16* wdB = (u16*)wsf;
    u16* wB1 = (u16*)((char*)wsf + WB1_BYTE);
    u16* wB2 = (u16*)((char*)wsf + WB2_BYTE);
    int idx = blockIdx.x * 256 + threadIdx.x;
    if (idx < 36864) {                        // wdB[co*576 + t*64 + ci]
        int co = idx / 576, r = idx % 576;
        int t = r >> 6, ci = r & 63;
        wdB[idx] = f2bf(wd[(co * 64 + ci) * 9 + t]);
    } else if (idx < 73728) {                 // wB1[co*576 + t*64 + ci]
        int j = idx - 36864;
        int co = j / 576, r = j % 576;
        int t = r >> 6, ci = r & 63;
        wB1[j] = f2bf(w1[(co * 64 + ci) * 9 + t]);
    } else if (idx < 82944) {                 // wB2[oc*64+ci]
        int j = idx - 73728;
        wB2[j] = f2bf(w2[j]);
    }
}

// K0b: x NCHW f32 -> NHWC bf16.
__global__ __launch_bounds__(256) void x_to_nhwc(const float* __restrict__ x,
                                                 u16* __restrict__ xt) {
    int p = blockIdx.x * 256 + threadIdx.x;          // global pixel
    if (p >= B_ * PLANE_IN) return;
    int b = p / PLANE_IN, pp = p % PLANE_IN;
    const float* xb = x + (size_t)b * CIN * PLANE_IN + pp;
    u16* dst = xt + (size_t)p * 64;
    #pragma unroll
    for (int oct = 0; oct < 8; ++oct) {
        union { u16 h[8]; uint4 q; } pk;
        #pragma unroll
        for (int j = 0; j < 8; ++j)
            pk.h[j] = f2bf(xb[(size_t)(oct * 8 + j) * PLANE_IN]);
        *(uint4*)(dst + oct * 8) = pk.q;
    }
}

// LDS for conv12: linear 128B rows + XOR swizzle byte ^= (p&7)<<4 (T2).
union ConvSmem {
    char xsb[324 * 128];       // 41472 B : halo tile [p][ci] swizzled
    char hsb[4][64 * 128];     // 32768 B : per-wave h buffer [pix][ci] swizzled
};
__device__ __forceinline__ int swz128(int row, int bytecol) {
    return row * 128 + (bytecol ^ ((row & 7) << 4));
}

// K1: fused conv1 (3x3 VALID, 64->64) + conv2 (1x1, 64->144) via bf16 MFMA.
template<bool XT>
__global__ __launch_bounds__(256) void conv12(const float* __restrict__ x,
                                              const u16* __restrict__ xt,
                                              const float* __restrict__ b1,
                                              const float* __restrict__ b2,
                                              const float* __restrict__ wsf,
                                              float* __restrict__ off_out) {
    __shared__ ConvSmem sm;
    const u16* wB1 = (const u16*)((const char*)wsf + WB1_BYTE);
    const u16* wB2 = (const u16*)((const char*)wsf + WB2_BYTE);
    const int b = blockIdx.z;
    const int y0 = blockIdx.y * 16, x0 = blockIdx.x * 16;
    const int tid = threadIdx.x;
    const int wave = tid >> 6, lane = tid & 63;
    const int n16 = lane & 15, quad = lane >> 4;

    if constexpr (XT) {
        const u16* xtb = xt + (size_t)b * PLANE_IN * 64;
        for (int idx = tid; idx < 324 * 8; idx += 256) {
            int p = idx >> 3, oct = idx & 7;
            *(bfrag*)(sm.xsb + swz128(p, oct * 16)) =
                *(const bfrag*)&xtb[((size_t)(y0 + p / 18) * W + x0 + p % 18) * 64 + oct * 8];
        }
    } else {
        const float* xb = x + (size_t)b * CIN * PLANE_IN;
        for (int idx = tid; idx < 324 * 64; idx += 256) {
            int ci = idx / 324, p = idx % 324;
            float v = xb[(size_t)ci * PLANE_IN + (y0 + p / 18) * W + (x0 + p % 18)];
            *(u16*)(sm.xsb + swz128(p, ci * 2)) = f2bf(v);
        }
    }
    __syncthreads();

    ffrag acc[4][4];
    #pragma unroll
    for (int nt = 0; nt < 4; ++nt) {
        float bv = b1[nt * 16 + n16];
        #pragma unroll
        for (int mt = 0; mt < 4; ++mt) acc[mt][nt] = ffrag{bv, bv, bv, bv};
    }

    #pragma unroll
    for (int s = 0; s < 18; ++s) {                    // K=576 in 18 slices of 32
        const int tap = s >> 1, cib = (s & 1) * 32;
        const int ti = tap / 3, tj = tap % 3;
        bfrag a[4], bb[4];
        #pragma unroll
        for (int mt = 0; mt < 4; ++mt) {              // A[m=lane&15][k=quad*8+j]
            int p = (wave * 4 + mt + ti) * 18 + n16 + tj;
            a[mt] = *(const bfrag*)(sm.xsb + swz128(p, cib * 2 + quad * 16));
        }
        #pragma unroll
        for (int nt = 0; nt < 4; ++nt)                // B[n=lane&15][k=quad*8+j]
            bb[nt] = *(const bfrag*)&wB1[(nt * 16 + n16) * 576 + tap * 64 + cib + quad * 8];
        #pragma unroll
        for (int mt = 0; mt < 4; ++mt)
            #pragma unroll
            for (int nt = 0; nt < 4; ++nt)
                acc[mt][nt] = __builtin_amdgcn_mfma_f32_16x16x32_bf16(
                    a[mt], bb[nt], acc[mt][nt], 0, 0, 0);
    }

    __syncthreads();

    #pragma unroll
    for (int mt = 0; mt < 4; ++mt)
        #pragma unroll
        for (int nt = 0; nt < 4; ++nt)
            #pragma unroll
            for (int r = 0; r < 4; ++r)
                *(u16*)(sm.hsb[wave] + swz128(mt * 16 + quad * 4 + r, (nt * 16 + n16) * 2))
                    = f2bf(acc[mt][nt][r]);
    __syncthreads();

    bfrag a2[4][2];
    #pragma unroll
    for (int mt = 0; mt < 4; ++mt)
        #pragma unroll
        for (int s2 = 0; s2 < 2; ++s2)
            a2[mt][s2] = *(const bfrag*)(sm.hsb[wave]
                        + swz128(mt * 16 + n16, s2 * 64 + quad * 16));

    float* offb = off_out + (size_t)b * OFFC * PLANE_OUT;
    #pragma unroll 1
    for (int nt2 = 0; nt2 < 9; ++nt2) {               // N2=144 in 9 n-tiles
        bfrag b2f[2];
        #pragma unroll
        for (int s2 = 0; s2 < 2; ++s2)
            b2f[s2] = *(const bfrag*)&wB2[(nt2 * 16 + n16) * 64 + s2 * 32 + quad * 8];
        float bv = b2[nt2 * 16 + n16];
        #pragma unroll
        for (int mt = 0; mt < 4; ++mt) {
            ffrag acc2 = ffrag{bv, bv, bv, bv};
            acc2 = __builtin_amdgcn_mfma_f32_16x16x32_bf16(a2[mt][0], b2f[0], acc2, 0, 0, 0);
            acc2 = __builtin_amdgcn_mfma_f32_16x16x32_bf16(a2[mt][1], b2f[1], acc2, 0, 0, 0);
            float* dst = offb + (size_t)(nt2 * 16 + n16) * PLANE_OUT
                       + (y0 + wave * 4 + mt) * WO + x0 + quad * 4;
            *(ffrag*)dst = acc2;
        }
    }
}

// by-value interp: no arrays, no pointers -> SROA-proof (anti scratch, rule #20)
__device__ __forceinline__ bfrag interp1(bfrag q0, bfrag q1, bfrag q2, bfrag q3,
                                         float w0, float w1, float w2, float w3) {
    union { u16 h[8]; bfrag f; } pk;
    #pragma unroll
    for (int j = 0; j < 8; ++j) {
        float v = w0 * bf2f(q0[j]) + w1 * bf2f(q1[j])
                + w2 * bf2f(q2[j]) + w3 * bf2f(q3[j]);
        pk.h[j] = f2bf(v);
    }
    return pk.f;
}

// K2: deformable conv via bf16 MFMA with LDS-staged bilinear gathers.
// Spill-proof schedule: per tap, per k-half {load 4 weight frags; per m-tile
// {compute 4 corner bfrags as named scalars (LDS, rare global fallback),
// interp by value, 4 MFMAs immediately}}. Nothing array-shaped crosses a
// branch; peak live ~90 VGPR.
constexpr int TR = 14, TC = 22, TILE_PX = TR * TC;    // 308 px, 39424 B

__device__ __forceinline__ bfrag lds_px(const char* xls, int p, int g) {
    return *(const bfrag*)(xls + p * 128 + ((g * 16) ^ ((p & 7) << 4)));
}

template<bool XT>
__global__ __launch_bounds__(256, 4) void deform_k(const float* __restrict__ x,
                                                   const u16* __restrict__ xt,
                                                   const float* __restrict__ wsf,
                                                   const float* __restrict__ off_in,
                                                   float* __restrict__ y_out) {
    __shared__ char xls[TILE_PX * 128];               // 39424 B
    const u16* wdB = (const u16*)wsf;

    const int wg = blockIdx.x;
    const int swz = (wg & 7) * 256 + (wg >> 3);       // XCD-contiguous, bijective (2048%8==0)
    const int b = swz >> 7, sp = swz & 127;
    const int y0 = (sp >> 3) * 8, x0 = (sp & 7) * 16;
    const int ylo = y0 - 2, xlo = x0 - 2;

    const int tid = threadIdx.x;
    const int wave = tid >> 6, lane = tid & 63;
    const int n16 = lane & 15, quad = lane >> 4;
    const int wo = x0 + n16;

    const float* offbase = off_in + (size_t)b * OFFC * PLANE_OUT + x0 + n16;
    const u16* xtb = xt + (size_t)b * PLANE_IN * 64;
    const float* xb = x + (size_t)b * CIN * PLANE_IN;

    if constexpr (XT) {
        for (int idx = tid; idx < TILE_PX * 8; idx += 256) {
            int oct = idx & 7, pix = idx >> 3;
            int ty = pix / TC, tx = pix % TC;
            int iy = min(max(ylo + ty, 0), H - 1);
            int ix = min(max(xlo + tx, 0), W - 1);
            *(bfrag*)(xls + pix * 128 + ((oct * 16) ^ ((pix & 7) << 4)))
                = *(const bfrag*)&xtb[((size_t)(iy * W + ix)) * 64 + oct * 8];
        }
        __syncthreads();
    }

    ffrag acc[2][4];
    #pragma unroll
    for (int mt = 0; mt < 2; ++mt)
        #pragma unroll
        for (int nt = 0; nt < 4; ++nt) acc[mt][nt] = ffrag{0.f, 0.f, 0.f, 0.f};

    // prefetched offsets for the upcoming tap; tk = mt*2 + half
    float pdy[4], pdx[4];
    #pragma unroll
    for (int tk = 0; tk < 4; ++tk) {
        const int mt = tk >> 1, g = quad + (tk & 1) * 4;
        const float* ob = offbase + (y0 + wave * 2 + mt) * WO
                        + (size_t)(g * 9 * 2) * PLANE_OUT;      // t = 0
        pdy[tk] = ob[0];
        pdx[tk] = ob[PLANE_OUT];
    }

    #pragma unroll 1
    for (int t = 0; t < 9; ++t) {
        const int ki = t / 3, kj = t % 3;

        float dyv[4], dxv[4];
        #pragma unroll
        for (int tk = 0; tk < 4; ++tk) { dyv[tk] = pdy[tk]; dxv[tk] = pdx[tk]; }

        if (t < 8) {                                  // prefetch next tap's offsets
            #pragma unroll
            for (int tk = 0; tk < 4; ++tk) {
                const int mt = tk >> 1, g = quad + (tk & 1) * 4;
                const float* ob = offbase + (y0 + wave * 2 + mt) * WO
                                + (size_t)((g * 9 + t + 1) * 2) * PLANE_OUT;
                pdy[tk] = ob[0];
                pdx[tk] = ob[PLANE_OUT];
            }
        }

        #pragma unroll
        for (int half = 0; half < 2; ++half) {
            const int g = quad + half * 4;
            // this k-half's B-operands only (16 VGPRs, scoped)
            bfrag bw0 = *(const bfrag*)&wdB[(size_t)(0 * 16 + n16) * 576 + t * 64 + half * 32 + quad * 8];
            bfrag bw1 = *(const bfrag*)&wdB[(size_t)(1 * 16 + n16) * 576 + t * 64 + half * 32 + quad * 8];
            bfrag bw2 = *(const bfrag*)&wdB[(size_t)(2 * 16 + n16) * 576 + t * 64 + half * 32 + quad * 8];
            bfrag bw3 = *(const bfrag*)&wdB[(size_t)(3 * 16 + n16) * 576 + t * 64 + half * 32 + quad * 8];

            #pragma unroll
            for (int mt = 0; mt < 2; ++mt) {
                const int tk = mt * 2 + half;
                const int ho = y0 + wave * 2 + mt;
                float py = dyv[tk] + (float)(ho + ki);
                float px = dxv[tk] + (float)(wo + kj);
                float y0f = floorf(py), x0f = floorf(px);
                float ly = py - y0f, lx = px - x0f;
                int yi0 = (int)y0f, xi0 = (int)x0f;
                int yi1 = yi0 + 1, xi1 = xi0 + 1;
                float vy0 = (yi0 >= 0 && yi0 < H) ? 1.f : 0.f;
                float vy1 = (yi1 >= 0 && yi1 < H) ? 1.f : 0.f;
                float vx0 = (xi0 >= 0 && xi0 < W) ? 1.f : 0.f;
                float vx1 = (xi1 >= 0 && xi1 < W) ? 1.f : 0.f;
                float w00 = (1.f - ly) * (1.f - lx) * vy0 * vx0;
                float w01 = (1.f - ly) * lx         * vy0 * vx1;
                float w10 = ly * (1.f - lx)         * vy1 * vx0;
                float w11 = ly * lx                 * vy1 * vx1;
                int yc0 = min(max(yi0, 0), H - 1), yc1 = min(max(yi1, 0), H - 1);
                int xc0 = min(max(xi0, 0), W - 1), xc1 = min(max(xi1, 0), W - 1);

                bfrag q00, q01, q10, q11;
                if constexpr (XT) {
                    int ry0 = yc0 - ylo, ry1 = yc1 - ylo;
                    int rx0 = xc0 - xlo, rx1 = xc1 - xlo;
                    bool intile = ((u32)ry0 < TR) & ((u32)ry1 < TR)
                                & ((u32)rx0 < TC) & ((u32)rx1 < TC);
                    if (intile) {
                        q00 = lds_px(xls, ry0 * TC + rx0, g);
                        q01 = lds_px(xls, ry0 * TC + rx1, g);
                        q10 = lds_px(xls, ry1 * TC + rx0, g);
                        q11 = lds_px(xls, ry1 * TC + rx1, g);
                    } else {                          // execz-skipped in practice
                        q00 = *(const bfrag*)&xtb[(size_t)(yc0 * W + xc0) * 64 + g * 8];
                        q01 = *(const bfrag*)&xtb[(size_t)(yc0 * W + xc1) * 64 + g * 8];
                        q10 = *(const bfrag*)&xtb[(size_t)(yc1 * W + xc0) * 64 + g * 8];
                        q11 = *(const bfrag*)&xtb[(size_t)(yc1 * W + xc1) * 64 + g * 8];
                    }
                } else {
                    int i00 = yc0 * W + xc0, i01 = yc0 * W + xc1;
                    int i10 = yc1 * W + xc0, i11 = yc1 * W + xc1;
                    const float* xg = xb + (size_t)g * CPG * PLANE_IN;
                    union { u16 h[8]; bfrag f; } p00, p01, p10, p11;
                    #pragma unroll
                    for (int cc = 0; cc < 8; ++cc) {
                        const float* xp = xg + cc * PLANE_IN;
                        p00.h[cc] = f2bf(xp[i00]); p01.h[cc] = f2bf(xp[i01]);
                        p10.h[cc] = f2bf(xp[i10]); p11.h[cc] = f2bf(xp[i11]);
                    }
                    q00 = p00.f; q01 = p01.f; q10 = p10.f; q11 = p11.f;
                }

                bfrag fr = interp1(q00, q01, q10, q11, w00, w01, w10, w11);

                acc[mt][0] = __builtin_amdgcn_mfma_f32_16x16x32_bf16(fr, bw0, acc[mt][0], 0, 0, 0);
                acc[mt][1] = __builtin_amdgcn_mfma_f32_16x16x32_bf16(fr, bw1, acc[mt][1], 0, 0, 0);
                acc[mt][2] = __builtin_amdgcn_mfma_f32_16x16x32_bf16(fr, bw2, acc[mt][2], 0, 0, 0);
                acc[mt][3] = __builtin_amdgcn_mfma_f32_16x16x32_bf16(fr, bw3, acc[mt][3], 0, 0, 0);
            }
        }
    }

    // epilogue: lane holds D[m=quad*4+r][n=n16]; m = pixel col, n = co-in-tile
    float* yb = y_out + (size_t)b * COUT * PLANE_OUT;
    #pragma unroll
    for (int nt = 0; nt < 4; ++nt)
        #pragma unroll
        for (int mt = 0; mt < 2; ++mt) {
            float* dst = yb + (size_t)(nt * 16 + n16) * PLANE_OUT
                       + (y0 + wave * 2 + mt) * WO + x0 + quad * 4;
            *(ffrag*)dst = acc[mt][nt];
        }
}

extern "C" void kernel_launch(void* const* d_in, const int* in_sizes, int n_in,
                              void* d_out, int out_size, void* d_ws, size_t ws_size,
                              hipStream_t stream) {
    const float* x  = (const float*)d_in[0];
    const float* w1 = (const float*)d_in[1];
    const float* b1 = (const float*)d_in[2];
    const float* w2 = (const float*)d_in[3];
    const float* b2 = (const float*)d_in[4];
    const float* wd = (const float*)d_in[5];
    float* y_out = (float*)d_out;
    float* off_out = y_out + (size_t)B_ * COUT * PLANE_OUT;   // (y, off) concat
    float* wsf = (float*)d_ws;
    u16* xt = (u16*)((char*)d_ws + XT_BYTE);
    const bool use_xt = ws_size >= XT_BYTE + XT_SIZE;

    prep_weights<<<324, 256, 0, stream>>>(w1, wd, w2, wsf);
    if (use_xt) {
        x_to_nhwc<<<(B_ * PLANE_IN + 255) / 256, 256, 0, stream>>>(x, xt);
        conv12<true><<<dim3(8, 8, B_), 256, 0, stream>>>(x, xt, b1, b2, wsf, off_out);
        deform_k<true><<<2048, 256, 0, stream>>>(x, xt, wsf, off_out, y_out);
    } else {
        conv12<false><<<dim3(8, 8, B_), 256, 0, stream>>>(x, xt, b1, b2, wsf, off_out);
        deform_k<false><<<2048, 256, 0, stream>>>(x, xt, wsf, off_out, y_out);
    }
}